// Round 16
// baseline (1015.998 us; speedup 1.0000x reference)
//
#include <hip/hip_runtime.h>
#include <stdint.h>

// TernaryMLP: relu-chain of h @ (gamma*T).T + b, T ternary (exact in bf16).
// gamma via deterministic fp64 2-stage reduction; bf16 MFMA GEMMs.
// Layers 1-3: 256^2-tile GEMM, 16x16x32 MFMA, 1 barrier/K-tile (R13 base).
//   R16: B stored as PACKED TERNARY i8 (exact) -> B staging bytes and B
//   ds_read count halved+; LDS 96KB. Packed K-layout (q,kk,e) so one
//   ds_read_b128 yields both k-halves of a B frag; 16B-granule swizzle
//   chunk^=(row&3) (bank-balanced, gload-compatible). i8->bf16 unpack in
//   VALU (underused pipe), slid under MFMA/port time by the scheduler.
// Layer 4 (N=1024): 128^2 2-phase GEMM with XOR swizzle (bf16 Q).
// Aux: cvt_bf16 fused into the absmean launch (blockIdx.y==4).

#define EPSQ 1e-5f

typedef __attribute__((ext_vector_type(8))) short bf16x8;   // 8 bf16 = 4 VGPR
typedef __attribute__((ext_vector_type(4))) float f32x4;    // MFMA accum
typedef __attribute__((ext_vector_type(4))) unsigned int u32x4;

__device__ __forceinline__ uint16_t f2bf(float f) {
    uint32_t u = __float_as_uint(f);
    return (uint16_t)((u + 0x7FFFu + ((u >> 16) & 1u)) >> 16);
}

__device__ __forceinline__ void load_lds16(const void* g, char* l) {
    __builtin_amdgcn_global_load_lds((const __attribute__((address_space(1))) void*)g,
                                     (__attribute__((address_space(3))) void*)l,
                                     16, 0, 0);
}

// 8 ternary i8 (two dwords) -> 8 bf16. Exact for {-1,0,+1}.
__device__ __forceinline__ bf16x8 unpack8(unsigned int x0, unsigned int x1) {
    union { unsigned int u[4]; bf16x8 v; } c;
    unsigned int xs0 = x0, xs1 = x1;
    {
        unsigned int e0 = (xs0 & 0xFFu) | ((xs0 & 0xFF00u) << 8);
        unsigned int e1 = ((xs0 >> 16) & 0xFFu) | ((xs0 >> 8) & 0x00FF0000u);
        c.u[0] = ((e0 & 0x00010001u) * 0x3F80u) | ((e0 & 0x00800080u) << 8);
        c.u[1] = ((e1 & 0x00010001u) * 0x3F80u) | ((e1 & 0x00800080u) << 8);
    }
    {
        unsigned int e0 = (xs1 & 0xFFu) | ((xs1 & 0xFF00u) << 8);
        unsigned int e1 = ((xs1 >> 16) & 0xFFu) | ((xs1 >> 8) & 0x00FF0000u);
        c.u[2] = ((e0 & 0x00010001u) * 0x3F80u) | ((e0 & 0x00800080u) << 8);
        c.u[3] = ((e1 & 0x00010001u) * 0x3F80u) | ((e1 & 0x00800080u) << 8);
    }
    return c.v;
}

// ---- gamma = mean(|W|) stage1 for 4 matrices + x->bf16 cvt, one launch ----
__global__ void absmean4_cvt(const float* __restrict__ w0, const float* __restrict__ w1,
                             const float* __restrict__ w2, const float* __restrict__ w3,
                             double* __restrict__ partial,
                             const float* __restrict__ x, uint16_t* __restrict__ y) {
    const int mi = blockIdx.y;
    if (mi == 4) {
        const long long n = 33554432LL;
        const long long stride = (long long)gridDim.x * blockDim.x * 4;
        for (long long i = ((long long)blockIdx.x * blockDim.x + threadIdx.x) * 4;
             i < n; i += stride) {
            float4 v = *(const float4*)(x + i);
            ushort4 o;
            o.x = f2bf(v.x); o.y = f2bf(v.y); o.z = f2bf(v.z); o.w = f2bf(v.w);
            *(ushort4*)(y + i) = o;
        }
        return;
    }
    const float* w = (mi == 0) ? w0 : (mi == 1) ? w1 : (mi == 2) ? w2 : w3;
    const long long n = (mi == 3) ? 4096000LL : 16777216LL;
    double acc = 0.0;
    const long long tid = (long long)blockIdx.x * blockDim.x + threadIdx.x;
    const long long stride = (long long)gridDim.x * blockDim.x;
    const float4* w4 = (const float4*)w;
    const long long n4 = n >> 2;
    for (long long i = tid; i < n4; i += stride) {
        float4 v = w4[i];
        acc += (double)fabsf(v.x) + (double)fabsf(v.y) +
               (double)fabsf(v.z) + (double)fabsf(v.w);
    }
    __shared__ double sm[256];
    sm[threadIdx.x] = acc;
    __syncthreads();
    for (int s = 128; s > 0; s >>= 1) {
        if ((int)threadIdx.x < s) sm[threadIdx.x] += sm[threadIdx.x + s];
        __syncthreads();
    }
    if (threadIdx.x == 0) partial[mi * 512 + blockIdx.x] = sm[0];
}

__global__ void absmean_stage2(const double* __restrict__ partial,
                               float* __restrict__ gammas) {
    const int m = blockIdx.x;
    __shared__ double sm[256];
    double acc = partial[m * 512 + threadIdx.x] + partial[m * 512 + 256 + threadIdx.x];
    sm[threadIdx.x] = acc;
    __syncthreads();
    for (int s = 128; s > 0; s >>= 1) {
        if ((int)threadIdx.x < s) sm[threadIdx.x] += sm[threadIdx.x + s];
        __syncthreads();
    }
    if (threadIdx.x == 0) {
        const double n = (m == 3) ? 1000.0 * 4096.0 : 4096.0 * 4096.0;
        gammas[m] = (float)(sm[0] / n);
    }
}

// ------- quantize W -> ternary bf16 (layer 4 path, + zero padding rows) -------
__global__ void quantize_w(const float* __restrict__ w, uint16_t* __restrict__ q,
                           long long n_valid, long long n_total,
                           const float* __restrict__ gammas, int gi) {
    const float d = gammas[gi] + EPSQ;
    const long long stride = (long long)gridDim.x * blockDim.x * 4;
    for (long long i = ((long long)blockIdx.x * blockDim.x + threadIdx.x) * 4;
         i < n_total; i += stride) {
        float4 v = make_float4(0.f, 0.f, 0.f, 0.f);
        if (i < n_valid) v = *(const float4*)(w + i);
        ushort4 o;
        o.x = f2bf(fminf(1.f, fmaxf(-1.f, rintf(v.x / d))));
        o.y = f2bf(fminf(1.f, fmaxf(-1.f, rintf(v.y / d))));
        o.z = f2bf(fminf(1.f, fmaxf(-1.f, rintf(v.z / d))));
        o.w = f2bf(fminf(1.f, fmaxf(-1.f, rintf(v.w / d))));
        *(ushort4*)(q + i) = o;
    }
}

// ------- quantize W -> packed ternary i8 (layers 1-3), K-permuted -------
// Within each 64-elem K-block: out byte [q*16 + kk*8 + e] = T[k = kk*32+q*8+e].
__global__ void quantize_w8(const float* __restrict__ w, uint8_t* __restrict__ q,
                            const float* __restrict__ gammas, int gi) {
    const float d = gammas[gi] + EPSQ;
    const long long total = 4096LL * 64;   // (n, kt) units
    const long long stride = (long long)gridDim.x * blockDim.x;
    for (long long u = (long long)blockIdx.x * blockDim.x + threadIdx.x;
         u < total; u += stride) {
        const long long n = u >> 6;
        const int kt = (int)(u & 63);
        const float* src = w + n * 4096 + kt * 64;
        unsigned int words[16];
#pragma unroll
        for (int di = 0; di < 16; ++di) {
            unsigned int wv = 0;
#pragma unroll
            for (int j = 0; j < 4; ++j) {
                const int g = di * 4 + j;
                const int qq = g >> 4, kk = (g >> 3) & 1, e = g & 7;
                float r = fminf(1.f, fmaxf(-1.f, rintf(src[kk * 32 + qq * 8 + e] / d)));
                wv |= ((unsigned int)((int)r & 0xFF)) << (8 * j);
            }
            words[di] = wv;
        }
        unsigned int* dst = (unsigned int*)(q + n * 4096 + kt * 64);
#pragma unroll
        for (int i = 0; i < 4; ++i)
            ((u32x4*)dst)[i] = (u32x4){words[4*i], words[4*i+1], words[4*i+2], words[4*i+3]};
    }
}

// ==== 256x256-tile GEMM, A bf16 in LDS + B packed-i8 in LDS (layers 1-3) ====
// C[m][n] = epi(gamma * sum_k A[m][k]*Bt[n][k] + bias[n])
// 512 thr = 8 waves (2M x 4N), per-wave 128x64 via 8x4 frags of 16x16.
// LDS 96KB: A buf[2]x32KB (256x64 bf16, XOR-swizzled (row&7)<<4) at 0;
//           B buf[2]x16KB (256 rows x 64B packed i8) at 65536.
// B swizzle: 16B chunk' = chunk ^ (row&3); staging = linear dest +
// inverse-swizzled source (rule #21). One b128 B-read = both kk halves.
template<bool RELU, bool BF16OUT>
__global__ __launch_bounds__(512, 2) void gemm256(
    const uint16_t* __restrict__ A, const uint8_t* __restrict__ Bq,
    const float* __restrict__ bias, const float* __restrict__ gammas, int gi,
    void* __restrict__ Cp, int K, int Nstore, int Nvalid, int gridN)
{
    __shared__ char lds[98304];

    const int tid  = threadIdx.x;
    const int lane = tid & 63;
    const int wid  = tid >> 6;
    const int wr   = wid >> 2;     // 0..1
    const int wc   = wid & 3;      // 0..3

    // T1: bijective XCD swizzle (gridDim.x % 8 == 0)
    const int nwg = gridDim.x;
    const int logical = ((int)blockIdx.x & 7) * (nwg >> 3) + ((int)blockIdx.x >> 3);
    const long long tileM = (long long)(logical / gridN) * 256;
    const long long tileN = (long long)(logical % gridN) * 256;

    // ---- A staging (inverse-swizzled source, linear LDS dest); 4 issues ----
    const int srowA = tid >> 3;                                  // 0..63
    const int scolA = (((tid & 7) ^ ((tid >> 3) & 7)) << 3);
    const uint16_t* As = A + (tileM + srowA) * (long long)K + scolA;

    auto stageA = [&](int par, int k0) {
        char* base = lds + par * 32768 + wid * 1024;
#pragma unroll
        for (int i = 0; i < 4; ++i)
            load_lds16(As + (long long)(i * 64) * K + k0, base + i * 8192);
    };

    // ---- B staging (packed i8): 2 issues of 8KB = 128 rows x 64B ----
    const int srowB = tid >> 2;                                  // 0..127
    const int schkB = ((tid & 3) ^ ((tid >> 2) & 3)) << 4;       // byte offset
    const uint8_t* Bs = Bq + (tileN + srowB) * (long long)K + schkB;

    auto stageB8 = [&](int par, int k0) {
        char* base = lds + 65536 + par * 16384 + tid * 16;
        load_lds16(Bs + k0, base);
        load_lds16(Bs + (long long)128 * K + k0, base + 8192);
    };

    // ---- fragment read addressing ----
    const int lr   = lane & 15;
    const int cb0  = (lane >> 4) << 4;
    const int swzA = (lane & 7) << 4;
    const int colk0 = cb0 ^ swzA;
    const int colk1 = (cb0 | 64) ^ swzA;
    const int Aoff = wr * 16384 + lr * 128;
    // B: row_local = wc*64 + n*16 + lr; chunk' = kq ^ (row&3)
    const int rl064 = (wc * 64 + lr) * 64;
    const int swzB  = (((lane >> 4) ^ (lr & 3)) << 4);

    f32x4 acc[8][4];
#pragma unroll
    for (int m = 0; m < 8; ++m)
#pragma unroll
        for (int n = 0; n < 4; ++n)
            acc[m][n] = (f32x4){0.f, 0.f, 0.f, 0.f};

    const int NT = K >> 6;

    // ---- prologue ----
    stageA(0, 0);
    stageB8(0, 0);
    asm volatile("s_waitcnt vmcnt(0)" ::: "memory");
    __builtin_amdgcn_s_barrier();

    for (int t = 0; t < NT; ++t) {
        const int par = t & 1;
        const char* Ab = lds + par * 32768 + Aoff;
        const char* Bb = lds + 65536 + par * 16384;

        // B reads first (4 x b128, both kk halves), then A kk0 reads
        u32x4 praw[4];
#pragma unroll
        for (int n = 0; n < 4; ++n)
            praw[n] = *(const u32x4*)(Bb + rl064 + n * 1024 + swzB);

        bf16x8 a[8];
#pragma unroll
        for (int m = 0; m < 8; ++m)
            a[m] = *(const bf16x8*)(Ab + m * 2048 + colk0);

        // next-tile staging (WAR-safe via previous tile-end barrier)
        if (t + 1 < NT) { stageA(par ^ 1, (t + 1) * 64); stageB8(par ^ 1, (t + 1) * 64); }

        // unpack kk0 B (compiler auto-waits praw; runs while A-reads drain)
        bf16x8 b0[4];
#pragma unroll
        for (int n = 0; n < 4; ++n)
            b0[n] = unpack8(praw[n][0], praw[n][1]);

        asm volatile("s_waitcnt lgkmcnt(0)" ::: "memory");
        __builtin_amdgcn_sched_barrier(0);   // rule #18 wall
#pragma unroll
        for (int m = 0; m < 8; ++m)
#pragma unroll
            for (int n = 0; n < 4; ++n)
                acc[m][n] = __builtin_amdgcn_mfma_f32_16x16x32_bf16(
                    a[m], b0[n], acc[m][n], 0, 0, 0);
        // (no wall: kk1 unpack + A kk1 reads may slide into cluster0's tail)

        bf16x8 b1v[4];
#pragma unroll
        for (int n = 0; n < 4; ++n)
            b1v[n] = unpack8(praw[n][2], praw[n][3]);
        bf16x8 a2[8];
#pragma unroll
        for (int m = 0; m < 8; ++m)
            a2[m] = *(const bf16x8*)(Ab + m * 2048 + colk1);
        asm volatile("s_waitcnt lgkmcnt(0)" ::: "memory");
        __builtin_amdgcn_sched_barrier(0);   // rule #18 wall
#pragma unroll
        for (int m = 0; m < 8; ++m)
#pragma unroll
            for (int n = 0; n < 4; ++n)
                acc[m][n] = __builtin_amdgcn_mfma_f32_16x16x32_bf16(
                    a2[m], b1v[n], acc[m][n], 0, 0, 0);

        if (t + 1 < NT)
            asm volatile("s_waitcnt vmcnt(0)" ::: "memory");
        __builtin_amdgcn_sched_barrier(0);
        __builtin_amdgcn_s_barrier();
    }

    // ---- epilogue: C/D 16x16: col=lane&15, row=(lane>>4)*4+j ----
    const float g = gammas[gi];
    const int cr = (lane >> 4) << 2;
    const int cc = lane & 15;
#pragma unroll
    for (int m = 0; m < 8; ++m) {
        const long long row = tileM + wr * 128 + m * 16 + cr;
#pragma unroll
        for (int n = 0; n < 4; ++n) {
            const int col = (int)tileN + wc * 64 + n * 16 + cc;
            if (col < Nvalid) {
                const float bb = bias[col];
#pragma unroll
                for (int j = 0; j < 4; ++j) {
                    float v = acc[m][n][j] * g + bb;
                    if (RELU) v = fmaxf(v, 0.f);
                    if (BF16OUT)
                        ((uint16_t*)Cp)[(row + j) * (long long)Nstore + col] = f2bf(v);
                    else
                        ((float*)Cp)[(row + j) * (long long)Nstore + col] = v;
                }
            }
        }
    }
}

// ================= 128x128-tile GEMM with swizzle (layer 4) =================
template<bool RELU, bool BF16OUT>
__global__ __launch_bounds__(256) void gemm_bt(
    const uint16_t* __restrict__ A, const uint16_t* __restrict__ Bt,
    const float* __restrict__ bias, const float* __restrict__ gammas, int gi,
    void* __restrict__ Cp, int K, int Nstore, int Nvalid)
{
    constexpr int BK = 64;
    __shared__ char Atile[128 * 128];
    __shared__ char Btile[128 * 128];

    const int tid  = threadIdx.x;
    const int lane = tid & 63;
    const int wv   = tid >> 6;
    const int wr   = wv >> 1, wc = wv & 1;
    const long long tileM = (long long)blockIdx.y * 128;
    const long long tileN = (long long)blockIdx.x * 128;

    const float g = gammas[gi];

    f32x4 acc[4][4];
#pragma unroll
    for (int m = 0; m < 4; ++m)
#pragma unroll
        for (int n = 0; n < 4; ++n)
            acc[m][n] = (f32x4){0.f, 0.f, 0.f, 0.f};

    const int sr = tid >> 3;
    const int sc = ((tid & 7) * 8) ^ (((tid >> 3) & 7) * 8);
    const uint16_t* Ag = A  + (tileM + sr) * K + sc;
    const uint16_t* Bg = Bt + (tileN + sr) * K + sc;
    char* Ad = Atile + tid * 16;
    char* Bd = Btile + tid * 16;

    const int lr = lane & 15;
    const int klane = (lane >> 4) * 16;
    const int swz = (lr & 7) << 4;

    const int kIters = K / BK;
    for (int kt = 0; kt < kIters; ++kt) {
        const long long k0 = (long long)kt * BK;
        __syncthreads();
#pragma unroll
        for (int i = 0; i < 4; ++i) {
            load_lds16(Ag + (long long)(i * 32) * K + k0, Ad + i * 4096);
            load_lds16(Bg + (long long)(i * 32) * K + k0, Bd + i * 4096);
        }
        __syncthreads();
#pragma unroll
        for (int kk2 = 0; kk2 < 2; ++kk2) {
            const int cb = (kk2 * 64 + klane) ^ swz;
            bf16x8 a[4], b[4];
#pragma unroll
            for (int m = 0; m < 4; ++m)
                a[m] = *(const bf16x8*)(Atile + (wr * 64 + m * 16 + lr) * 128 + cb);
#pragma unroll
            for (int n = 0; n < 4; ++n)
                b[n] = *(const bf16x8*)(Btile + (wc * 64 + n * 16 + lr) * 128 + cb);
#pragma unroll
            for (int m = 0; m < 4; ++m)
#pragma unroll
                for (int n = 0; n < 4; ++n)
                    acc[m][n] = __builtin_amdgcn_mfma_f32_16x16x32_bf16(
                        a[m], b[n], acc[m][n], 0, 0, 0);
        }
    }

    const int cr = (lane >> 4) * 4;
    const int cc = lane & 15;
#pragma unroll
    for (int m = 0; m < 4; ++m) {
        const long long row = tileM + wr * 64 + m * 16 + cr;
#pragma unroll
        for (int n = 0; n < 4; ++n) {
            const int col = (int)tileN + wc * 64 + n * 16 + cc;
            if (col < Nvalid) {
                const float bb = bias[col];
#pragma unroll
                for (int j = 0; j < 4; ++j) {
                    float v = acc[m][n][j] * g + bb;
                    if (RELU) v = fmaxf(v, 0.f);
                    if (BF16OUT)
                        ((uint16_t*)Cp)[(row + j) * (long long)Nstore + col] = f2bf(v);
                    else
                        ((float*)Cp)[(row + j) * (long long)Nstore + col] = v;
                }
            }
        }
    }
}

extern "C" void kernel_launch(void* const* d_in, const int* in_sizes, int n_in,
                              void* d_out, int out_size, void* d_ws, size_t ws_size,
                              hipStream_t stream) {
    const float* x  = (const float*)d_in[0];
    const float* W1 = (const float*)d_in[1];
    const float* b1 = (const float*)d_in[2];
    const float* W2 = (const float*)d_in[3];
    const float* b2 = (const float*)d_in[4];
    const float* W3 = (const float*)d_in[5];
    const float* b3 = (const float*)d_in[6];
    const float* W4 = (const float*)d_in[7];
    const float* b4 = (const float*)d_in[8];
    float* out = (float*)d_out;

    const long long B = 8192, D = 4096, H = 4096, C = 1000, CPAD = 1024;

    // ws: gammas | partials | Q bf16 (8MB, layer4) | Qi8 (16MB) | HA | HB
    char* ws = (char*)d_ws;
    float*  gammas  = (float*)ws;
    double* partial = (double*)(ws + 256);
    uint16_t* Q   = (uint16_t*)(ws + 32768);
    uint8_t*  Qi8 = (uint8_t*)(ws + 32768 + 8388608);
    uint16_t* HA  = (uint16_t*)(ws + 32768 + 8388608 + 16777216);
    uint16_t* HB  = HA + (size_t)(B * H);

    const long long nW4 = C * D;

    absmean4_cvt<<<dim3(512, 5), 256, 0, stream>>>(W1, W2, W3, W4, partial, x, HA);
    absmean_stage2<<<4, 256, 0, stream>>>(partial, gammas);

    const int gridN = (int)(H / 256);           // 16
    const int nwg   = gridN * (int)(B / 256);   // 512

    quantize_w8<<<1024, 256, 0, stream>>>(W1, Qi8, gammas, 0);
    gemm256<true, true><<<dim3(nwg), dim3(512), 0, stream>>>(
        HA, Qi8, b1, gammas, 0, HB, (int)D, (int)H, (int)H, gridN);
    quantize_w8<<<1024, 256, 0, stream>>>(W2, Qi8, gammas, 1);
    gemm256<true, true><<<dim3(nwg), dim3(512), 0, stream>>>(
        HB, Qi8, b2, gammas, 1, HA, (int)H, (int)H, (int)H, gridN);
    quantize_w8<<<1024, 256, 0, stream>>>(W3, Qi8, gammas, 2);
    gemm256<true, true><<<dim3(nwg), dim3(512), 0, stream>>>(
        HA, Qi8, b3, gammas, 2, HB, (int)H, (int)H, (int)H, gridN);
    quantize_w<<<2048, 256, 0, stream>>>(W4, Q, nW4, CPAD * D, gammas, 3);
    gemm_bt<false, false><<<dim3((unsigned)(CPAD / 128), (unsigned)(B / 128)),
                            dim3(256), 0, stream>>>(
        HB, Q, b4, gammas, 3, out, (int)H, (int)C, (int)C);
}